// Round 13
// baseline (583.866 us; speedup 1.0000x reference)
//
#include <hip/hip_runtime.h>
#include <math.h>

#define D_   16
#define H_   56
#define W_   56
#define CIN  32
#define COUT 64
#define KPTS 27
#define NCH  81                  // 3*KPTS offset channels
#define NP   (D_*H_*W_)          // 50176 output positions
#define CHW  (D_*H_*W_)          // per-channel plane size
#define KPAD 28                  // 27 deform points padded to f4 multiple

typedef float f4 __attribute__((ext_vector_type(4)));

static __device__ __forceinline__ int iclamp(int v, int lo, int hi) {
    return v < lo ? lo : (v > hi ? hi : v);
}

// ---------------------------------------------------------------------------
// Prep 1: weight transposes.
//   weight [COUT][CIN][27taps] -> wT  [tap][c][o]     (o contiguous)
//   offw   [81ch][CIN][27taps] -> owT [tap][d][c][28] (kpt contiguous, padded)
// ---------------------------------------------------------------------------
__global__ __launch_bounds__(256) void k_prep(const float* __restrict__ w,
                                              const float* __restrict__ ow,
                                              float* __restrict__ wT,
                                              float* __restrict__ owT) {
    int i = blockIdx.x * 256 + threadIdx.x;
    if (i < COUT * CIN * KPTS) {
        int tap = i % KPTS;
        int c   = (i / KPTS) % CIN;
        int o   = i / (KPTS * CIN);
        wT[(tap * CIN + c) * COUT + o] = w[i];
    }
    if (i < NCH * CIN * KPTS) {
        int tap = i % KPTS;
        int c   = (i / KPTS) % CIN;
        int ch  = i / (KPTS * CIN);
        int d   = ch % 3;
        int kpt = ch / 3;
        owT[(((tap * 3) + d) * CIN + c) * KPAD + kpt] = ow[i];
    }
    if (i < KPTS * 3 * CIN)                      // zero the pad slot
        owT[i * KPAD + 27] = 0.0f;
}

// ---------------------------------------------------------------------------
// Prep 2: out[o][p] = bias[o]  (k_dconv accumulates into it atomically)
// ---------------------------------------------------------------------------
__global__ __launch_bounds__(256) void k_init(const float* __restrict__ bias,
                                              float* __restrict__ out) {
    const int i   = blockIdx.x * 256 + threadIdx.x;  // float4 index
    const float b = bias[(i * 4) / NP];              // NP % 4 == 0
    f4 v; v.x = b; v.y = b; v.z = b; v.w = b;
    ((f4*)out)[i] = v;
}

// ---------------------------------------------------------------------------
// Kernel A: dense 3x3x3 conv -> offset channels, fused base-grid add.
// blockIdx.y = d. CHANNELS-FIRST x: per (tap,c) lane p reads x[c*CHW+sidx(p)],
// consecutive lanes -> consecutive addresses (fully coalesced scalar loads).
// 27(+pad) accumulators in NAMED f4 registers A0..A6.
// ---------------------------------------------------------------------------
__global__ __launch_bounds__(64, 2) void k_offsets(const float* __restrict__ x,
                                                   const float* __restrict__ owT,
                                                   const float* __restrict__ offb,
                                                   float* __restrict__ coords) {
    const int tid = threadIdx.x;
    const int p   = blockIdx.x * 64 + tid;
    const int d   = blockIdx.y;                      // uniform per block
    const int ox  = p % W_;
    const int t   = p / W_;
    const int oy  = t % H_;
    const int oz  = t / H_;

    f4 A0, A1, A2, A3, A4, A5, A6;
#define INIT4(Ai, kb) { f4 v; \
    v.x = offb[((kb) + 0) * 3 + d]; \
    v.y = offb[((kb) + 1) * 3 + d]; \
    v.z = offb[((kb) + 2) * 3 + d]; \
    v.w = ((kb) + 3 < KPTS) ? offb[((kb) + 3) * 3 + d] : 0.0f; \
    Ai = v; }
    INIT4(A0, 0) INIT4(A1, 4) INIT4(A2, 8) INIT4(A3, 12)
    INIT4(A4, 16) INIT4(A5, 20) INIT4(A6, 24)
#undef INIT4

    for (int tap = 0; tap < KPTS; ++tap) {
        const int kz = tap / 9, ky = (tap / 3) % 3, kx = tap % 3;
        const int zi = oz - 1 + kz, yi = oy - 1 + ky, xi = ox - 1 + kx;
        const bool val = ((unsigned)zi < (unsigned)D_) &&
                         ((unsigned)yi < (unsigned)H_) &&
                         ((unsigned)xi < (unsigned)W_);
        const int sidx = (iclamp(zi, 0, D_ - 1) * H_ + iclamp(yi, 0, H_ - 1)) * W_
                       + iclamp(xi, 0, W_ - 1);
        const float m = val ? 1.0f : 0.0f;

        // uniform weight slice for (tap, d): [c][28]; 7 f4 per channel
        const f4* w4 = (const f4*)(owT + (size_t)((tap * 3 + d) * CIN) * KPAD);
#pragma unroll 4
        for (int c = 0; c < CIN; ++c) {
            const float xv = m * x[c * CHW + sidx];  // coalesced scalar load
            const f4* wp = w4 + c * 7;
            A0 += wp[0] * xv; A1 += wp[1] * xv; A2 += wp[2] * xv;
            A3 += wp[3] * xv; A4 += wp[4] * xv; A5 += wp[5] * xv;
            A6 += wp[6] * xv;
        }
    }

    // coords[d][kpt][p] = offset + base-grid component
#define BASEF(kk) ((d == 0) ? (float)(oz - 1 + (kk) / 9) \
                 : (d == 1) ? (float)(oy - 1 + ((kk) / 3) % 3) \
                            : (float)(ox - 1 + (kk) % 3))
#define WOUT(Ai, kb) { \
    coords[(d * KPTS + (kb) + 0) * NP + p] = Ai.x + BASEF((kb) + 0); \
    coords[(d * KPTS + (kb) + 1) * NP + p] = Ai.y + BASEF((kb) + 1); \
    coords[(d * KPTS + (kb) + 2) * NP + p] = Ai.z + BASEF((kb) + 2); \
    if ((kb) + 3 < KPTS) \
        coords[(d * KPTS + (kb) + 3) * NP + p] = Ai.w + BASEF((kb) + 3); }
    WOUT(A0, 0) WOUT(A1, 4) WOUT(A2, 8) WOUT(A3, 12)
    WOUT(A4, 16) WOUT(A5, 20) WOUT(A6, 24)
#undef WOUT
#undef BASEF
}

// ---------------------------------------------------------------------------
// Kernel B: fused trilinear sampling + contraction. blockIdx.y = tap group
// (9 taps). CHANNELS-FIRST x: per (tap,c) the 8 corner loads are scalar and
// coalesced across lanes (consecutive positions -> ~consecutive addresses).
// 64 out-channels in NAMED f4 registers A0..A15; atomicAdd into bias-inited out.
// ---------------------------------------------------------------------------
__global__ __launch_bounds__(64, 2) void k_dconv(const float* __restrict__ x,
                                                 const float* __restrict__ coords,
                                                 const float* __restrict__ wT,
                                                 float* __restrict__ out) {
    const int tid = threadIdx.x;
    const int p   = blockIdx.x * 64 + tid;
    const int g   = blockIdx.y;                      // 0..2, taps [9g, 9g+9)

    f4 A0 = 0, A1 = 0, A2 = 0, A3 = 0, A4 = 0, A5 = 0, A6 = 0, A7 = 0;
    f4 A8 = 0, A9 = 0, A10 = 0, A11 = 0, A12 = 0, A13 = 0, A14 = 0, A15 = 0;

    for (int tap = 9 * g; tap < 9 * g + 9; ++tap) {
        const float cz = coords[(0 * KPTS + tap) * NP + p];
        const float cy = coords[(1 * KPTS + tap) * NP + p];
        const float cx = coords[(2 * KPTS + tap) * NP + p];

        const float zf = floorf(cz), yf = floorf(cy), xf = floorf(cx);
        const float fz = cz - zf, fy = cy - yf, fx = cx - xf;
        const int z0 = (int)zf, y0 = (int)yf, x0 = (int)xf;

        float cw0, cw1, cw2, cw3, cw4, cw5, cw6, cw7;
        int   cb0, cb1, cb2, cb3, cb4, cb5, cb6, cb7;
#define CORNER(jj, Wj, Bj) { \
    const int dz_ = (jj) >> 2, dy_ = ((jj) >> 1) & 1, dx_ = (jj) & 1; \
    const int zi_ = z0 + dz_, yi_ = y0 + dy_, xi_ = x0 + dx_; \
    const bool v_ = ((unsigned)zi_ < (unsigned)D_) && \
                    ((unsigned)yi_ < (unsigned)H_) && \
                    ((unsigned)xi_ < (unsigned)W_); \
    const float wz_ = dz_ ? fz : 1.0f - fz; \
    const float wy_ = dy_ ? fy : 1.0f - fy; \
    const float wx_ = dx_ ? fx : 1.0f - fx; \
    Wj = v_ ? wz_ * wy_ * wx_ : 0.0f; \
    Bj = (iclamp(zi_, 0, D_ - 1) * H_ + iclamp(yi_, 0, H_ - 1)) * W_ \
         + iclamp(xi_, 0, W_ - 1); }
        CORNER(0, cw0, cb0) CORNER(1, cw1, cb1) CORNER(2, cw2, cb2)
        CORNER(3, cw3, cb3) CORNER(4, cw4, cb4) CORNER(5, cw5, cb5)
        CORNER(6, cw6, cb6) CORNER(7, cw7, cb7)
#undef CORNER

        // uniform weight slice for tap: [c][o], 16 f4 per channel
        const float* wtap = wT + (size_t)tap * CIN * COUT;
#pragma unroll 4
        for (int c = 0; c < CIN; ++c) {
            const float* xc = x + c * CHW;
            const float v0 = xc[cb0], v1 = xc[cb1], v2 = xc[cb2], v3 = xc[cb3];
            const float v4 = xc[cb4], v5 = xc[cb5], v6 = xc[cb6], v7 = xc[cb7];
            const float s = cw0 * v0 + cw1 * v1 + cw2 * v2 + cw3 * v3
                          + cw4 * v4 + cw5 * v5 + cw6 * v6 + cw7 * v7;
            const f4* wq = (const f4*)(wtap + c * COUT);
            A0  += wq[0]  * s; A1  += wq[1]  * s; A2  += wq[2]  * s; A3  += wq[3]  * s;
            A4  += wq[4]  * s; A5  += wq[5]  * s; A6  += wq[6]  * s; A7  += wq[7]  * s;
            A8  += wq[8]  * s; A9  += wq[9]  * s; A10 += wq[10] * s; A11 += wq[11] * s;
            A12 += wq[12] * s; A13 += wq[13] * s; A14 += wq[14] * s; A15 += wq[15] * s;
        }
    }

    float* op = out + p;
#define AOUT(Ai, ob) { \
    atomicAdd(op + ((ob) + 0) * NP, Ai.x); atomicAdd(op + ((ob) + 1) * NP, Ai.y); \
    atomicAdd(op + ((ob) + 2) * NP, Ai.z); atomicAdd(op + ((ob) + 3) * NP, Ai.w); }
    AOUT(A0, 0)  AOUT(A1, 4)  AOUT(A2, 8)   AOUT(A3, 12)
    AOUT(A4, 16) AOUT(A5, 20) AOUT(A6, 24)  AOUT(A7, 28)
    AOUT(A8, 32) AOUT(A9, 36) AOUT(A10, 40) AOUT(A11, 44)
    AOUT(A12, 48) AOUT(A13, 52) AOUT(A14, 56) AOUT(A15, 60)
#undef AOUT
}

// ---------------------------------------------------------------------------
extern "C" void kernel_launch(void* const* d_in, const int* in_sizes, int n_in,
                              void* d_out, int out_size, void* d_ws, size_t ws_size,
                              hipStream_t stream) {
    const float* x    = (const float*)d_in[0];  // [32,16,56,56]
    const float* offw = (const float*)d_in[1];  // [81,32,3,3,3]
    const float* offb = (const float*)d_in[2];  // [81]
    const float* wgt  = (const float*)d_in[3];  // [64,32,3,3,3]
    const float* bias = (const float*)d_in[4];  // [64]
    float* out = (float*)d_out;                 // [64,16,56,56]

    float* ws     = (float*)d_ws;
    float* coords = ws;                            // 3*27*NP       (~16.3 MB)
    float* wT     = coords + 3 * KPTS * NP;        // 27*32*64
    float* owT    = wT + KPTS * CIN * COUT;        // 27*3*32*28

    const int n_tr = NCH * CIN * KPTS;             // 69984
    hipLaunchKernelGGL(k_prep, dim3((n_tr + 255) / 256), dim3(256), 0, stream,
                       wgt, offw, wT, owT);
    hipLaunchKernelGGL(k_init, dim3(COUT * NP / 4 / 256), dim3(256), 0, stream,
                       bias, out);
    hipLaunchKernelGGL(k_offsets, dim3(NP / 64, 3), dim3(64), 0, stream,
                       x, owT, offb, coords);
    hipLaunchKernelGGL(k_dconv, dim3(NP / 64, 3), dim3(64), 0, stream,
                       x, coords, wT, out);
}

// Round 15
// 537.218 us; speedup vs baseline: 1.0868x; 1.0868x over previous
//
#include <hip/hip_runtime.h>
#include <math.h>

#define D_   16
#define H_   56
#define W_   56
#define CIN  32
#define COUT 64
#define KPTS 27
#define NCH  81                  // 3*KPTS offset channels
#define NP   (D_*H_*W_)          // 50176 output positions
#define CHW  (D_*H_*W_)          // per-channel plane size
#define KPAD 28                  // 27 deform points padded to f4 multiple

typedef float f4 __attribute__((ext_vector_type(4)));

static __device__ __forceinline__ int iclamp(int v, int lo, int hi) {
    return v < lo ? lo : (v > hi ? hi : v);
}

// ---------------------------------------------------------------------------
// Prep 1: weight transposes.
//   weight [COUT][CIN][27taps] -> wT  [tap][c][o]     (o contiguous)
//   offw   [81ch][CIN][27taps] -> owT [tap][d][c][28] (kpt contiguous, padded)
// ---------------------------------------------------------------------------
__global__ __launch_bounds__(256) void k_prep(const float* __restrict__ w,
                                              const float* __restrict__ ow,
                                              float* __restrict__ wT,
                                              float* __restrict__ owT) {
    int i = blockIdx.x * 256 + threadIdx.x;
    if (i < COUT * CIN * KPTS) {
        int tap = i % KPTS;
        int c   = (i / KPTS) % CIN;
        int o   = i / (KPTS * CIN);
        wT[(tap * CIN + c) * COUT + o] = w[i];
    }
    if (i < NCH * CIN * KPTS) {
        int tap = i % KPTS;
        int c   = (i / KPTS) % CIN;
        int ch  = i / (KPTS * CIN);
        int d   = ch % 3;
        int kpt = ch / 3;
        owT[(((tap * 3) + d) * CIN + c) * KPAD + kpt] = ow[i];
    }
    if (i < KPTS * 3 * CIN)                      // zero the pad slot
        owT[i * KPAD + 27] = 0.0f;
}

// ---------------------------------------------------------------------------
// Prep 2: out[o][p] = bias[o]  (k_dconv tap-group partials atomicAdd into it)
// ---------------------------------------------------------------------------
__global__ __launch_bounds__(256) void k_init(const float* __restrict__ bias,
                                              float* __restrict__ out) {
    const int i   = blockIdx.x * 256 + threadIdx.x;  // float4 index
    const float b = bias[(i * 4) / NP];              // NP % 4 == 0
    f4 v; v.x = b; v.y = b; v.z = b; v.w = b;
    ((f4*)out)[i] = v;
}

// ---------------------------------------------------------------------------
// Prep 3: coords[d][k][p] = offb[k*3+d] + base(d,k,p)
// (k_offsets tap-group partials atomicAdd into this)
// ---------------------------------------------------------------------------
__global__ __launch_bounds__(256) void k_init_coords(const float* __restrict__ offb,
                                                     float* __restrict__ coords) {
    const int i  = blockIdx.x * 256 + threadIdx.x;   // over 81*NP, grid exact
    const int p  = i % NP;
    const int ck = i / NP;                           // d*27 + k
    const int d  = ck / KPTS;
    const int k  = ck % KPTS;
    const int kz = k / 9, ky = (k / 3) % 3, kx = k % 3;
    const int x  = p % W_;
    const int y  = (p / W_) % H_;
    const int z  = p / (W_ * H_);
    const float base = (d == 0) ? (float)(z - 1 + kz)
                     : (d == 1) ? (float)(y - 1 + ky)
                                : (float)(x - 1 + kx);
    coords[i] = offb[k * 3 + d] + base;
}

// ---------------------------------------------------------------------------
// Kernel A: dense 3x3x3 conv -> offset channel partials (one 9-tap group,
// one coord component d). blockIdx.y = d*3 + tg -> grid (784,9), 7056 waves.
// CHANNELS-FIRST x: loads coalesced across lanes. atomicAdd into pre-inited
// coords. (Split validated round 11: ~220 -> ~130 us; loads round 13.)
// ---------------------------------------------------------------------------
__global__ __launch_bounds__(64, 2) void k_offsets(const float* __restrict__ x,
                                                   const float* __restrict__ owT,
                                                   float* __restrict__ coords) {
    const int tid = threadIdx.x;
    const int p   = blockIdx.x * 64 + tid;
    const int by  = blockIdx.y;
    const int d   = by / 3;                          // coord component
    const int tg  = by % 3;                          // tap group
    const int ox  = p % W_;
    const int t   = p / W_;
    const int oy  = t % H_;
    const int oz  = t / H_;

    f4 A0 = 0, A1 = 0, A2 = 0, A3 = 0, A4 = 0, A5 = 0, A6 = 0;

    for (int tap = 9 * tg; tap < 9 * tg + 9; ++tap) {
        const int kz = tap / 9, ky = (tap / 3) % 3, kx = tap % 3;
        const int zi = oz - 1 + kz, yi = oy - 1 + ky, xi = ox - 1 + kx;
        const bool val = ((unsigned)zi < (unsigned)D_) &&
                         ((unsigned)yi < (unsigned)H_) &&
                         ((unsigned)xi < (unsigned)W_);
        const int sidx = (iclamp(zi, 0, D_ - 1) * H_ + iclamp(yi, 0, H_ - 1)) * W_
                       + iclamp(xi, 0, W_ - 1);
        const float m = val ? 1.0f : 0.0f;

        // uniform weight slice for (tap, d): [c][28]; 7 f4 per channel
        const f4* w4 = (const f4*)(owT + (size_t)((tap * 3 + d) * CIN) * KPAD);
#pragma unroll 4
        for (int c = 0; c < CIN; ++c) {
            const float xv = m * x[c * CHW + sidx];  // coalesced scalar load
            const f4* wp = w4 + c * 7;
            A0 += wp[0] * xv; A1 += wp[1] * xv; A2 += wp[2] * xv;
            A3 += wp[3] * xv; A4 += wp[4] * xv; A5 += wp[5] * xv;
            A6 += wp[6] * xv;
        }
    }

    float* cp = coords + (size_t)d * KPTS * NP + p;
#define COUTA(Ai, kb) { \
    atomicAdd(cp + ((kb) + 0) * NP, Ai.x); \
    atomicAdd(cp + ((kb) + 1) * NP, Ai.y); \
    atomicAdd(cp + ((kb) + 2) * NP, Ai.z); \
    if ((kb) + 3 < KPTS) atomicAdd(cp + ((kb) + 3) * NP, Ai.w); }
    COUTA(A0, 0) COUTA(A1, 4) COUTA(A2, 8) COUTA(A3, 12)
    COUTA(A4, 16) COUTA(A5, 20) COUTA(A6, 24)
#undef COUTA
}

// ---------------------------------------------------------------------------
// Kernel B: fused trilinear sampling + contraction partial (3 taps/block).
// blockIdx.y = g 0..8 -> grid (784,9), 7056 waves (~86% grid occupancy).
// CHANNELS-FIRST coalesced corner loads; 64 out-channels in NAMED f4 regs;
// atomicAdd into bias-inited out. Tap-split does NOT duplicate gather work.
// ---------------------------------------------------------------------------
__global__ __launch_bounds__(64, 2) void k_dconv(const float* __restrict__ x,
                                                 const float* __restrict__ coords,
                                                 const float* __restrict__ wT,
                                                 float* __restrict__ out) {
    const int tid = threadIdx.x;
    const int p   = blockIdx.x * 64 + tid;
    const int g   = blockIdx.y;                      // 0..8, taps [3g, 3g+3)

    f4 A0 = 0, A1 = 0, A2 = 0, A3 = 0, A4 = 0, A5 = 0, A6 = 0, A7 = 0;
    f4 A8 = 0, A9 = 0, A10 = 0, A11 = 0, A12 = 0, A13 = 0, A14 = 0, A15 = 0;

    for (int tap = 3 * g; tap < 3 * g + 3; ++tap) {
        const float cz = coords[(0 * KPTS + tap) * NP + p];
        const float cy = coords[(1 * KPTS + tap) * NP + p];
        const float cx = coords[(2 * KPTS + tap) * NP + p];

        const float zf = floorf(cz), yf = floorf(cy), xf = floorf(cx);
        const float fz = cz - zf, fy = cy - yf, fx = cx - xf;
        const int z0 = (int)zf, y0 = (int)yf, x0 = (int)xf;

        float cw0, cw1, cw2, cw3, cw4, cw5, cw6, cw7;
        int   cb0, cb1, cb2, cb3, cb4, cb5, cb6, cb7;
#define CORNER(jj, Wj, Bj) { \
    const int dz_ = (jj) >> 2, dy_ = ((jj) >> 1) & 1, dx_ = (jj) & 1; \
    const int zi_ = z0 + dz_, yi_ = y0 + dy_, xi_ = x0 + dx_; \
    const bool v_ = ((unsigned)zi_ < (unsigned)D_) && \
                    ((unsigned)yi_ < (unsigned)H_) && \
                    ((unsigned)xi_ < (unsigned)W_); \
    const float wz_ = dz_ ? fz : 1.0f - fz; \
    const float wy_ = dy_ ? fy : 1.0f - fy; \
    const float wx_ = dx_ ? fx : 1.0f - fx; \
    Wj = v_ ? wz_ * wy_ * wx_ : 0.0f; \
    Bj = (iclamp(zi_, 0, D_ - 1) * H_ + iclamp(yi_, 0, H_ - 1)) * W_ \
         + iclamp(xi_, 0, W_ - 1); }
        CORNER(0, cw0, cb0) CORNER(1, cw1, cb1) CORNER(2, cw2, cb2)
        CORNER(3, cw3, cb3) CORNER(4, cw4, cb4) CORNER(5, cw5, cb5)
        CORNER(6, cw6, cb6) CORNER(7, cw7, cb7)
#undef CORNER

        // uniform weight slice for tap: [c][o], 16 f4 per channel
        const float* wtap = wT + (size_t)tap * CIN * COUT;
#pragma unroll 4
        for (int c = 0; c < CIN; ++c) {
            const float* xc = x + c * CHW;
            const float v0 = xc[cb0], v1 = xc[cb1], v2 = xc[cb2], v3 = xc[cb3];
            const float v4 = xc[cb4], v5 = xc[cb5], v6 = xc[cb6], v7 = xc[cb7];
            const float s = cw0 * v0 + cw1 * v1 + cw2 * v2 + cw3 * v3
                          + cw4 * v4 + cw5 * v5 + cw6 * v6 + cw7 * v7;
            const f4* wq = (const f4*)(wtap + c * COUT);
            A0  += wq[0]  * s; A1  += wq[1]  * s; A2  += wq[2]  * s; A3  += wq[3]  * s;
            A4  += wq[4]  * s; A5  += wq[5]  * s; A6  += wq[6]  * s; A7  += wq[7]  * s;
            A8  += wq[8]  * s; A9  += wq[9]  * s; A10 += wq[10] * s; A11 += wq[11] * s;
            A12 += wq[12] * s; A13 += wq[13] * s; A14 += wq[14] * s; A15 += wq[15] * s;
        }
    }

    float* op = out + p;
#define AOUT(Ai, ob) { \
    atomicAdd(op + ((ob) + 0) * NP, Ai.x); atomicAdd(op + ((ob) + 1) * NP, Ai.y); \
    atomicAdd(op + ((ob) + 2) * NP, Ai.z); atomicAdd(op + ((ob) + 3) * NP, Ai.w); }
    AOUT(A0, 0)  AOUT(A1, 4)  AOUT(A2, 8)   AOUT(A3, 12)
    AOUT(A4, 16) AOUT(A5, 20) AOUT(A6, 24)  AOUT(A7, 28)
    AOUT(A8, 32) AOUT(A9, 36) AOUT(A10, 40) AOUT(A11, 44)
    AOUT(A12, 48) AOUT(A13, 52) AOUT(A14, 56) AOUT(A15, 60)
#undef AOUT
}

// ---------------------------------------------------------------------------
extern "C" void kernel_launch(void* const* d_in, const int* in_sizes, int n_in,
                              void* d_out, int out_size, void* d_ws, size_t ws_size,
                              hipStream_t stream) {
    const float* x    = (const float*)d_in[0];  // [32,16,56,56]
    const float* offw = (const float*)d_in[1];  // [81,32,3,3,3]
    const float* offb = (const float*)d_in[2];  // [81]
    const float* wgt  = (const float*)d_in[3];  // [64,32,3,3,3]
    const float* bias = (const float*)d_in[4];  // [64]
    float* out = (float*)d_out;                 // [64,16,56,56]

    float* ws     = (float*)d_ws;
    float* coords = ws;                            // 3*27*NP       (~16.3 MB)
    float* wT     = coords + 3 * KPTS * NP;        // 27*32*64
    float* owT    = wT + KPTS * CIN * COUT;        // 27*3*32*28

    const int n_tr = NCH * CIN * KPTS;             // 69984
    hipLaunchKernelGGL(k_prep, dim3((n_tr + 255) / 256), dim3(256), 0, stream,
                       wgt, offw, wT, owT);
    hipLaunchKernelGGL(k_init, dim3(COUT * NP / 4 / 256), dim3(256), 0, stream,
                       bias, out);
    hipLaunchKernelGGL(k_init_coords, dim3(NCH * NP / 256), dim3(256), 0, stream,
                       offb, coords);
    hipLaunchKernelGGL(k_offsets, dim3(NP / 64, 9), dim3(64), 0, stream,
                       x, owT, coords);
    hipLaunchKernelGGL(k_dconv, dim3(NP / 64, 9), dim3(64), 0, stream,
                       x, coords, wT, out);
}